// Round 2
// baseline (589.456 us; speedup 1.0000x reference)
//
#include <hip/hip_runtime.h>

#define N 512
#define C 128
#define H 128
#define R (N * N)  // 262144 rows

typedef __attribute__((ext_vector_type(8))) short short8;  // 8 x bf16 (4 VGPRs)
typedef __attribute__((ext_vector_type(4))) float f32x4;

static __device__ __forceinline__ ushort f2bf(float f) {
  union { float f; unsigned int u; } x; x.f = f;
  unsigned int r = (x.u + 0x7fffu + ((x.u >> 16) & 1u)) >> 16;  // RNE
  return (ushort)r;
}
static __device__ __forceinline__ float bf2f(ushort u) {
  union { unsigned int i; float f; } x; x.i = ((unsigned int)u) << 16; return x.f;
}
static __device__ __forceinline__ float sig(float x) { return 1.f / (1.f + __expf(-x)); }

// ---------------- Kernel 1: fused LN(C) + 5-way projection -----------------
// 128-row tile/block, 8 waves (16 rows each). LN over C computed in-kernel
// (fp32 pair -> bf16 z tile in LDS), then 5 GEMMs against K=128-resident
// weights. a = (z@Wa^T+ba)*sig(z@Ga^T+bga) -> a_t[h][row] (h-major for the
// einsum); b likewise -> b_t; g_o = sig(z@Wg^T+bg) -> bf16 [row][c].
__global__ __launch_bounds__(512) void k_proj(
    const float* __restrict__ pair,
    const float* __restrict__ ln_g, const float* __restrict__ ln_b,
    const float* __restrict__ Wa, const float* __restrict__ ba,
    const float* __restrict__ Ga, const float* __restrict__ bga,
    const float* __restrict__ Wb, const float* __restrict__ bb,
    const float* __restrict__ Gb, const float* __restrict__ bgb,
    const float* __restrict__ Wg, const float* __restrict__ bg,
    ushort* __restrict__ a_t, ushort* __restrict__ b_t, ushort* __restrict__ g_o) {
  __shared__ ushort zt[128 * 128];   // LN'd z tile, swizzled, 32 KB
  __shared__ ushort wt[128 * 128];   // current weight matrix, swizzled, 32 KB
  __shared__ ushort ot[128 * 136];   // transpose staging [h][row], 34 KB (136-pad => 272B rows, 16B-aligned)
  const int t = threadIdx.x, lane = t & 63, wid = t >> 6;
  const long base = (long)blockIdx.x * 128;

  // --- fused LayerNorm over C: wave handles 16 rows, lane covers 2 channels
  const float2 gg = *reinterpret_cast<const float2*>(ln_g + lane * 2);
  const float2 gb = *reinterpret_cast<const float2*>(ln_b + lane * 2);
#pragma unroll
  for (int rr = 0; rr < 16; ++rr) {
    int row = wid * 16 + rr;
    const float2 v = *reinterpret_cast<const float2*>(pair + (base + row) * C + lane * 2);
    float s = v.x + v.y, ss = v.x * v.x + v.y * v.y;
#pragma unroll
    for (int off = 1; off < 64; off <<= 1) {
      s += __shfl_xor(s, off);
      ss += __shfl_xor(ss, off);
    }
    const float mu = s * (1.f / C);
    const float rs = rsqrtf(ss * (1.f / C) - mu * mu + 1e-5f);
    ushort2 o;
    o.x = f2bf((v.x - mu) * rs * gg.x + gb.x);
    o.y = f2bf((v.y - mu) * rs * gg.y + gb.y);
    // swizzled store: 4B granule; chunk-index XOR consistent with 16B reads
    *reinterpret_cast<ushort2*>(reinterpret_cast<char*>(zt) + row * 256 + ((lane * 4) ^ ((row & 7) << 4))) = o;
  }

  auto stage_w = [&](const float* __restrict__ W) {
#pragma unroll
    for (int s2 = 0; s2 < 8; ++s2) {
      int id = t + s2 * 512;             // [0,4096) float4 units
      int row = id >> 5, hb = id & 31;
      float4 v = *reinterpret_cast<const float4*>(W + row * 128 + hb * 4);
      ushort4 o = make_ushort4(f2bf(v.x), f2bf(v.y), f2bf(v.z), f2bf(v.w));
      *reinterpret_cast<ushort4*>(reinterpret_cast<char*>(wt) + row * 256 + ((hb * 8) ^ ((row & 7) << 4))) = o;
    }
  };

  const int arow = wid * 16 + (lane & 15);
  const int abase = arow * 256, asw = (arow & 7) << 4;
  const int kb0 = (lane >> 4) * 16;

  f32x4 accL[8], accG[8];
  auto mfma_pass = [&](f32x4* acc) {
#pragma unroll
    for (int n2 = 0; n2 < 8; ++n2) acc[n2] = (f32x4)0.f;
#pragma unroll
    for (int kk = 0; kk < 4; ++kk) {
      int kbyte = kk * 64 + kb0;
      short8 af = *reinterpret_cast<const short8*>(reinterpret_cast<char*>(zt) + abase + (kbyte ^ asw));
#pragma unroll
      for (int n2 = 0; n2 < 8; ++n2) {
        int brow = n2 * 16 + (lane & 15);
        short8 bfr = *reinterpret_cast<const short8*>(reinterpret_cast<char*>(wt) + brow * 256 + (kbyte ^ ((brow & 7) << 4)));
        acc[n2] = __builtin_amdgcn_mfma_f32_16x16x32_bf16(af, bfr, acc[n2], 0, 0, 0);
      }
    }
  };

  auto combine_store = [&](const float* __restrict__ bl, const float* __restrict__ bg2,
                           ushort* __restrict__ dst) {
    // fragment -> ot[h][row] (bf16): lane writes rows r..r+3 contiguously (8B)
#pragma unroll
    for (int n2 = 0; n2 < 8; ++n2) {
      int col = n2 * 16 + (lane & 15);
      float b1 = bl[col], b2 = bg2[col];
      union { ushort4 v; ushort e[4]; } o;
#pragma unroll
      for (int r = 0; r < 4; ++r)
        o.e[r] = f2bf((accL[n2][r] + b1) * sig(accG[n2][r] + b2));
      int rowb = wid * 16 + (lane >> 4) * 4;
      *reinterpret_cast<ushort4*>(reinterpret_cast<char*>(ot) + col * 272 + rowb * 2) = o.v;
    }
    __syncthreads();
    // coalesced h-major global write: 256B per h-line
#pragma unroll
    for (int s2 = 0; s2 < 4; ++s2) {
      int id = t + s2 * 512;
      int h = id >> 4, part = id & 15;
      short8 v = *reinterpret_cast<const short8*>(reinterpret_cast<char*>(ot) + h * 272 + part * 16);
      *reinterpret_cast<short8*>(dst + (long)h * R + base + part * 8) = v;
    }
  };

  stage_w(Wa); __syncthreads(); mfma_pass(accL); __syncthreads();
  stage_w(Ga); __syncthreads(); mfma_pass(accG); __syncthreads();
  combine_store(ba, bga, a_t); __syncthreads();
  stage_w(Wb); __syncthreads(); mfma_pass(accL); __syncthreads();
  stage_w(Gb); __syncthreads(); mfma_pass(accG); __syncthreads();
  combine_store(bb, bgb, b_t); __syncthreads();
  stage_w(Wg); __syncthreads(); mfma_pass(accL);
#pragma unroll
  for (int n2 = 0; n2 < 8; ++n2) {
    int col = n2 * 16 + (lane & 15);
    float b1 = bg[col];
#pragma unroll
    for (int r = 0; r < 4; ++r) {
      long row = base + wid * 16 + (lane >> 4) * 4 + r;
      g_o[row * 128 + col] = f2bf(sig(accL[n2][r] + b1));
    }
  }
}

// ---------------- Kernel 2: einsum = 128 x (512x512x512) NT GEMMs ----------
// t[h][i][j] = sum_k a_t[h][i][k] * b_t[h][j][k].  128x128 tile, BK=64, 4 waves.
__global__ __launch_bounds__(256) void k_einsum(const ushort* __restrict__ a_t,
                                                const ushort* __restrict__ b_t,
                                                ushort* __restrict__ t_out) {
  __shared__ ushort As[128 * 64];  // 16 KB, swizzled
  __shared__ ushort Bs[128 * 64];
  const int t = threadIdx.x, lane = t & 63, wid = t >> 6;
  const int h = blockIdx.y;
  const int ti = blockIdx.x >> 2, tj = blockIdx.x & 3;
  const ushort* A = a_t + (long)h * R;
  const ushort* B = b_t + (long)h * R;
  const int wm = wid >> 1, wn = wid & 1;  // 2x2 wave grid, 64x64 per wave

  f32x4 acc[4][4];
#pragma unroll
  for (int m = 0; m < 4; ++m)
#pragma unroll
    for (int n2 = 0; n2 < 4; ++n2) acc[m][n2] = (f32x4)0.f;

  for (int kt = 0; kt < 8; ++kt) {
    __syncthreads();
#pragma unroll
    for (int s2 = 0; s2 < 4; ++s2) {
      int id = t + s2 * 256;            // [0,1024): row(128) x kc(8) 16B chunks
      int row = id >> 3, kc = id & 7;
      int sbo = row * 128 + ((kc * 16) ^ ((row & 7) << 4));
      *reinterpret_cast<short8*>(reinterpret_cast<char*>(As) + sbo) =
          *reinterpret_cast<const short8*>(A + (ti * 128 + row) * 512 + kt * 64 + kc * 8);
      *reinterpret_cast<short8*>(reinterpret_cast<char*>(Bs) + sbo) =
          *reinterpret_cast<const short8*>(B + (tj * 128 + row) * 512 + kt * 64 + kc * 8);
    }
    __syncthreads();
#pragma unroll
    for (int kk = 0; kk < 2; ++kk) {
      int kbyte = kk * 64 + (lane >> 4) * 16;
      short8 af[4], bfr[4];
#pragma unroll
      for (int m = 0; m < 4; ++m) {
        int row = wm * 64 + m * 16 + (lane & 15);
        af[m] = *reinterpret_cast<const short8*>(reinterpret_cast<char*>(As) + row * 128 + (kbyte ^ ((row & 7) << 4)));
      }
#pragma unroll
      for (int n2 = 0; n2 < 4; ++n2) {
        int row = wn * 64 + n2 * 16 + (lane & 15);
        bfr[n2] = *reinterpret_cast<const short8*>(reinterpret_cast<char*>(Bs) + row * 128 + (kbyte ^ ((row & 7) << 4)));
      }
#pragma unroll
      for (int m = 0; m < 4; ++m)
#pragma unroll
        for (int n2 = 0; n2 < 4; ++n2)
          acc[m][n2] = __builtin_amdgcn_mfma_f32_16x16x32_bf16(af[m], bfr[n2], acc[m][n2], 0, 0, 0);
    }
  }
  ushort* T = t_out + (long)h * R;
#pragma unroll
  for (int m = 0; m < 4; ++m) {
    int row0 = ti * 128 + wm * 64 + m * 16 + (lane >> 4) * 4;
#pragma unroll
    for (int n2 = 0; n2 < 4; ++n2) {
      int col = tj * 128 + wn * 64 + n2 * 16 + (lane & 15);
#pragma unroll
      for (int r = 0; r < 4; ++r) T[(row0 + r) * 512 + col] = f2bf(acc[m][n2][r]);
    }
  }
}

// ---------------- Kernel 3: LN over H + @Wo^T + gating ---------------------
__global__ __launch_bounds__(512) void k_out(
    const ushort* __restrict__ t_in, const ushort* __restrict__ g_o,
    const float* __restrict__ lg, const float* __restrict__ lb,
    const float* __restrict__ Wo, const float* __restrict__ bo,
    float* __restrict__ out) {
  __shared__ ushort tt[128 * 132];   // raw t tile, transposed [row][h], pad 132
  __shared__ ushort zb[128 * 128];   // LN output bf16, swizzled
  __shared__ ushort wt[128 * 128];   // Wo bf16, swizzled
  const int t = threadIdx.x, lane = t & 63, wid = t >> 6;
  const long base = (long)blockIdx.x * 128;

  // stage t (h-major -> [row][h] in LDS)
#pragma unroll
  for (int s2 = 0; s2 < 4; ++s2) {
    int id = t + s2 * 512;
    int h = id >> 4, part = id & 15;
    short8 v = *reinterpret_cast<const short8*>(t_in + (long)h * R + base + part * 8);
#pragma unroll
    for (int r = 0; r < 8; ++r) tt[(part * 8 + r) * 132 + h] = (ushort)v[r];
  }
  // stage Wo (fp32 -> bf16, swizzled)
#pragma unroll
  for (int s2 = 0; s2 < 8; ++s2) {
    int id = t + s2 * 512;
    int row = id >> 5, hb = id & 31;
    float4 v = *reinterpret_cast<const float4*>(Wo + row * 128 + hb * 4);
    ushort4 o = make_ushort4(f2bf(v.x), f2bf(v.y), f2bf(v.z), f2bf(v.w));
    *reinterpret_cast<ushort4*>(reinterpret_cast<char*>(wt) + row * 256 + ((hb * 8) ^ ((row & 7) << 4))) = o;
  }
  __syncthreads();
  // LN over h: wave handles 16 rows, lane covers 2 h
#pragma unroll
  for (int rr = 0; rr < 16; ++rr) {
    int row = wid * 16 + rr;
    ushort2 u = *reinterpret_cast<const ushort2*>(tt + row * 132 + lane * 2);
    float x0 = bf2f(u.x), x1 = bf2f(u.y);
    float s = x0 + x1, ss = x0 * x0 + x1 * x1;
#pragma unroll
    for (int off = 1; off < 64; off <<= 1) { s += __shfl_xor(s, off); ss += __shfl_xor(ss, off); }
    float mu = s * (1.f / H);
    float rs = rsqrtf(ss * (1.f / H) - mu * mu + 1e-5f);
    ushort2 ov;
    ov.x = f2bf((x0 - mu) * rs * lg[lane * 2] + lb[lane * 2]);
    ov.y = f2bf((x1 - mu) * rs * lg[lane * 2 + 1] + lb[lane * 2 + 1]);
    *reinterpret_cast<ushort2*>(reinterpret_cast<char*>(zb) + row * 256 + ((lane * 4) ^ ((row & 7) << 4))) = ov;
  }
  __syncthreads();

  f32x4 acc[8];
#pragma unroll
  for (int n2 = 0; n2 < 8; ++n2) acc[n2] = (f32x4)0.f;
  const int arow = wid * 16 + (lane & 15);
  const int kb0 = (lane >> 4) * 16;
#pragma unroll
  for (int kk = 0; kk < 4; ++kk) {
    int kbyte = kk * 64 + kb0;
    short8 af = *reinterpret_cast<const short8*>(reinterpret_cast<char*>(zb) + arow * 256 + (kbyte ^ ((arow & 7) << 4)));
#pragma unroll
    for (int n2 = 0; n2 < 8; ++n2) {
      int brow = n2 * 16 + (lane & 15);
      short8 bfr = *reinterpret_cast<const short8*>(reinterpret_cast<char*>(wt) + brow * 256 + (kbyte ^ ((brow & 7) << 4)));
      acc[n2] = __builtin_amdgcn_mfma_f32_16x16x32_bf16(af, bfr, acc[n2], 0, 0, 0);
    }
  }
#pragma unroll
  for (int n2 = 0; n2 < 8; ++n2) {
    int col = n2 * 16 + (lane & 15);
    float b1 = bo[col];
#pragma unroll
    for (int r = 0; r < 4; ++r) {
      long row = base + wid * 16 + (lane >> 4) * 4 + r;
      out[row * 128 + col] = (acc[n2][r] + b1) * bf2f(g_o[row * 128 + col]);
    }
  }
}

extern "C" void kernel_launch(void* const* d_in, const int* in_sizes, int n_in,
                              void* d_out, int out_size, void* d_ws, size_t ws_size,
                              hipStream_t stream) {
  const float* pair  = (const float*)d_in[0];
  const float* ln_g  = (const float*)d_in[1];
  const float* ln_b  = (const float*)d_in[2];
  const float* lnh_g = (const float*)d_in[3];
  const float* lnh_b = (const float*)d_in[4];
  const float* Wa  = (const float*)d_in[5];
  const float* ba  = (const float*)d_in[6];
  const float* Ga  = (const float*)d_in[7];
  const float* bga = (const float*)d_in[8];
  const float* Wb  = (const float*)d_in[9];
  const float* bb  = (const float*)d_in[10];
  const float* Gb  = (const float*)d_in[11];
  const float* bgb = (const float*)d_in[12];
  const float* Wo  = (const float*)d_in[13];
  const float* bo  = (const float*)d_in[14];
  const float* Wg  = (const float*)d_in[15];
  const float* bg  = (const float*)d_in[16];
  float* out = (float*)d_out;

  // workspace: 4 x 64 MiB = 256 MiB total
  char* ws = (char*)d_ws;
  ushort* a_t = (ushort*)(ws);                    // 64 MiB  bf16 [H][R]
  ushort* b_t = (ushort*)(ws + 67108864);         // 64 MiB  bf16 [H][R]
  ushort* t_w = (ushort*)(ws + 134217728);        // 64 MiB  bf16 [H][R]
  ushort* g_o = (ushort*)(ws + 201326592);        // 64 MiB  bf16 [R][C]

  k_proj<<<R / 128, 512, 0, stream>>>(pair, ln_g, ln_b, Wa, ba, Ga, bga, Wb, bb, Gb, bgb, Wg, bg, a_t, b_t, g_o);
  k_einsum<<<dim3(16, 128), 256, 0, stream>>>(a_t, b_t, t_w);
  k_out<<<R / 128, 512, 0, stream>>>(t_w, g_o, lnh_g, lnh_b, Wo, bo, out);
}

// Round 5
// 575.159 us; speedup vs baseline: 1.0249x; 1.0249x over previous
//
#include <hip/hip_runtime.h>

#define N 512
#define C 128
#define H 128
#define R (N * N)  // 262144 rows

typedef __attribute__((ext_vector_type(8))) short short8;  // 8 x bf16 (4 VGPRs)
typedef __attribute__((ext_vector_type(4))) float f32x4;

static __device__ __forceinline__ ushort f2bf(float f) {
  union { float f; unsigned int u; } x; x.f = f;
  unsigned int r = (x.u + 0x7fffu + ((x.u >> 16) & 1u)) >> 16;  // RNE
  return (ushort)r;
}
static __device__ __forceinline__ float bf2f(ushort u) {
  union { unsigned int i; float f; } x; x.i = ((unsigned int)u) << 16; return x.f;
}
static __device__ __forceinline__ float sig(float x) { return 1.f / (1.f + __expf(-x)); }

// ---------------- Kernel 1: fused LN(C) + 5-way projection -----------------
// 128-row tile/block, 8 waves (16 rows each). LN over C computed in-kernel
// (fp32 pair -> bf16 z tile in LDS), then 5 GEMMs against K=128-resident
// weights. a = (z@Wa^T+ba)*sig(z@Ga^T+bga) -> a_t[h][row] (h-major for the
// einsum); b likewise -> b_t; g_o = sig(z@Wg^T+bg) -> bf16 [row][c].
__global__ __launch_bounds__(512) void k_proj(
    const float* __restrict__ pair,
    const float* __restrict__ ln_g, const float* __restrict__ ln_b,
    const float* __restrict__ Wa, const float* __restrict__ ba,
    const float* __restrict__ Ga, const float* __restrict__ bga,
    const float* __restrict__ Wb, const float* __restrict__ bb,
    const float* __restrict__ Gb, const float* __restrict__ bgb,
    const float* __restrict__ Wg, const float* __restrict__ bg,
    ushort* __restrict__ a_t, ushort* __restrict__ b_t, ushort* __restrict__ g_o) {
  __shared__ ushort zt[128 * 128];   // LN'd z tile, swizzled, 32 KB
  __shared__ ushort wt[128 * 128];   // current weight matrix, swizzled, 32 KB
  __shared__ ushort ot[128 * 136];   // transpose staging [h][row], 34 KB (136-pad => 272B rows, 16B-aligned)
  const int t = threadIdx.x, lane = t & 63, wid = t >> 6;
  const long base = (long)blockIdx.x * 128;

  // --- fused LayerNorm over C: wave handles 16 rows, lane covers 2 channels
  const float2 gg = *reinterpret_cast<const float2*>(ln_g + lane * 2);
  const float2 gb = *reinterpret_cast<const float2*>(ln_b + lane * 2);
#pragma unroll
  for (int rr = 0; rr < 16; ++rr) {
    int row = wid * 16 + rr;
    const float2 v = *reinterpret_cast<const float2*>(pair + (base + row) * C + lane * 2);
    float s = v.x + v.y, ss = v.x * v.x + v.y * v.y;
#pragma unroll
    for (int off = 1; off < 64; off <<= 1) {
      s += __shfl_xor(s, off);
      ss += __shfl_xor(ss, off);
    }
    const float mu = s * (1.f / C);
    const float rs = rsqrtf(ss * (1.f / C) - mu * mu + 1e-5f);
    ushort2 o;
    o.x = f2bf((v.x - mu) * rs * gg.x + gb.x);
    o.y = f2bf((v.y - mu) * rs * gg.y + gb.y);
    // swizzled store: 4B granule; chunk-index XOR consistent with 16B reads
    *reinterpret_cast<ushort2*>(reinterpret_cast<char*>(zt) + row * 256 + ((lane * 4) ^ ((row & 7) << 4))) = o;
  }

  auto stage_w = [&](const float* __restrict__ W) {
#pragma unroll
    for (int s2 = 0; s2 < 8; ++s2) {
      int id = t + s2 * 512;             // [0,4096) float4 units
      int row = id >> 5, hb = id & 31;
      float4 v = *reinterpret_cast<const float4*>(W + row * 128 + hb * 4);
      ushort4 o = make_ushort4(f2bf(v.x), f2bf(v.y), f2bf(v.z), f2bf(v.w));
      *reinterpret_cast<ushort4*>(reinterpret_cast<char*>(wt) + row * 256 + ((hb * 8) ^ ((row & 7) << 4))) = o;
    }
  };

  const int arow = wid * 16 + (lane & 15);
  const int abase = arow * 256, asw = (arow & 7) << 4;
  const int kb0 = (lane >> 4) * 16;

  f32x4 accL[8], accG[8];
  auto mfma_pass = [&](f32x4* acc) {
#pragma unroll
    for (int n2 = 0; n2 < 8; ++n2) acc[n2] = (f32x4)0.f;
#pragma unroll
    for (int kk = 0; kk < 4; ++kk) {
      int kbyte = kk * 64 + kb0;
      short8 af = *reinterpret_cast<const short8*>(reinterpret_cast<char*>(zt) + abase + (kbyte ^ asw));
#pragma unroll
      for (int n2 = 0; n2 < 8; ++n2) {
        int brow = n2 * 16 + (lane & 15);
        short8 bfr = *reinterpret_cast<const short8*>(reinterpret_cast<char*>(wt) + brow * 256 + (kbyte ^ ((brow & 7) << 4)));
        acc[n2] = __builtin_amdgcn_mfma_f32_16x16x32_bf16(af, bfr, acc[n2], 0, 0, 0);
      }
    }
  };

  auto combine_store = [&](const float* __restrict__ bl, const float* __restrict__ bg2,
                           ushort* __restrict__ dst) {
    // fragment -> ot[h][row] (bf16): lane writes rows r..r+3 contiguously (8B)
#pragma unroll
    for (int n2 = 0; n2 < 8; ++n2) {
      int col = n2 * 16 + (lane & 15);
      float b1 = bl[col], b2 = bg2[col];
      union { ushort4 v; ushort e[4]; } o;
#pragma unroll
      for (int r = 0; r < 4; ++r)
        o.e[r] = f2bf((accL[n2][r] + b1) * sig(accG[n2][r] + b2));
      int rowb = wid * 16 + (lane >> 4) * 4;
      *reinterpret_cast<ushort4*>(reinterpret_cast<char*>(ot) + col * 272 + rowb * 2) = o.v;
    }
    __syncthreads();
    // coalesced h-major global write: 256B per h-line
#pragma unroll
    for (int s2 = 0; s2 < 4; ++s2) {
      int id = t + s2 * 512;
      int h = id >> 4, part = id & 15;
      short8 v = *reinterpret_cast<const short8*>(reinterpret_cast<char*>(ot) + h * 272 + part * 16);
      *reinterpret_cast<short8*>(dst + (long)h * R + base + part * 8) = v;
    }
  };

  stage_w(Wa); __syncthreads(); mfma_pass(accL); __syncthreads();
  stage_w(Ga); __syncthreads(); mfma_pass(accG); __syncthreads();
  combine_store(ba, bga, a_t); __syncthreads();
  stage_w(Wb); __syncthreads(); mfma_pass(accL); __syncthreads();
  stage_w(Gb); __syncthreads(); mfma_pass(accG); __syncthreads();
  combine_store(bb, bgb, b_t); __syncthreads();
  stage_w(Wg); __syncthreads(); mfma_pass(accL);
#pragma unroll
  for (int n2 = 0; n2 < 8; ++n2) {
    int col = n2 * 16 + (lane & 15);
    float b1 = bg[col];
#pragma unroll
    for (int r = 0; r < 4; ++r) {
      long row = base + wid * 16 + (lane >> 4) * 4 + r;
      g_o[row * 128 + col] = f2bf(sig(accL[n2][r] + b1));
    }
  }
}

// ---------------- Kernel 2: einsum = 128 x (512x512x512) NT GEMMs ----------
// t[h][i][j] = sum_k a_t[h][i][k] * b_t[h][j][k].  128x128 tile, BK=64, 4 waves.
// ONLY change vs round-2-passing: flat-2048 launch + bijective XCD-chunked
// relabel (2048 = 8*256) so all 16 tiles of one h share an XCD L2.
__global__ __launch_bounds__(256) void k_einsum(const ushort* __restrict__ a_t,
                                                const ushort* __restrict__ b_t,
                                                ushort* __restrict__ t_out) {
  __shared__ ushort As[128 * 64];  // 16 KB, swizzled
  __shared__ ushort Bs[128 * 64];
  const int t = threadIdx.x, lane = t & 63, wid = t >> 6;
  const int flat = blockIdx.x;                 // 2048 = 8*256, bijective swizzle
  const int swz = (flat & 7) * 256 + (flat >> 3);
  const int h = swz >> 4, ti = (swz >> 2) & 3, tj = swz & 3;
  const ushort* A = a_t + (long)h * R;
  const ushort* B = b_t + (long)h * R;
  const int wm = wid >> 1, wn = wid & 1;  // 2x2 wave grid, 64x64 per wave

  f32x4 acc[4][4];
#pragma unroll
  for (int m = 0; m < 4; ++m)
#pragma unroll
    for (int n2 = 0; n2 < 4; ++n2) acc[m][n2] = (f32x4)0.f;

  for (int kt = 0; kt < 8; ++kt) {
    __syncthreads();
#pragma unroll
    for (int s2 = 0; s2 < 4; ++s2) {
      int id = t + s2 * 256;            // [0,1024): row(128) x kc(8) 16B chunks
      int row = id >> 3, kc = id & 7;
      int sbo = row * 128 + ((kc * 16) ^ ((row & 7) << 4));
      *reinterpret_cast<short8*>(reinterpret_cast<char*>(As) + sbo) =
          *reinterpret_cast<const short8*>(A + (ti * 128 + row) * 512 + kt * 64 + kc * 8);
      *reinterpret_cast<short8*>(reinterpret_cast<char*>(Bs) + sbo) =
          *reinterpret_cast<const short8*>(B + (tj * 128 + row) * 512 + kt * 64 + kc * 8);
    }
    __syncthreads();
#pragma unroll
    for (int kk = 0; kk < 2; ++kk) {
      int kbyte = kk * 64 + (lane >> 4) * 16;
      short8 af[4], bfr[4];
#pragma unroll
      for (int m = 0; m < 4; ++m) {
        int row = wm * 64 + m * 16 + (lane & 15);
        af[m] = *reinterpret_cast<const short8*>(reinterpret_cast<char*>(As) + row * 128 + (kbyte ^ ((row & 7) << 4)));
      }
#pragma unroll
      for (int n2 = 0; n2 < 4; ++n2) {
        int row = wn * 64 + n2 * 16 + (lane & 15);
        bfr[n2] = *reinterpret_cast<const short8*>(reinterpret_cast<char*>(Bs) + row * 128 + (kbyte ^ ((row & 7) << 4)));
      }
#pragma unroll
      for (int m = 0; m < 4; ++m)
#pragma unroll
        for (int n2 = 0; n2 < 4; ++n2)
          acc[m][n2] = __builtin_amdgcn_mfma_f32_16x16x32_bf16(af[m], bfr[n2], acc[m][n2], 0, 0, 0);
    }
  }
  ushort* T = t_out + (long)h * R;
#pragma unroll
  for (int m = 0; m < 4; ++m) {
    int row0 = ti * 128 + wm * 64 + m * 16 + (lane >> 4) * 4;
#pragma unroll
    for (int n2 = 0; n2 < 4; ++n2) {
      int col = tj * 128 + wn * 64 + n2 * 16 + (lane & 15);
#pragma unroll
      for (int r = 0; r < 4; ++r) T[(row0 + r) * 512 + col] = f2bf(acc[m][n2][r]);
    }
  }
}

// ---------------- Kernel 3: LN over H + @Wo^T + gating ---------------------
__global__ __launch_bounds__(512) void k_out(
    const ushort* __restrict__ t_in, const ushort* __restrict__ g_o,
    const float* __restrict__ lg, const float* __restrict__ lb,
    const float* __restrict__ Wo, const float* __restrict__ bo,
    float* __restrict__ out) {
  __shared__ ushort tt[128 * 132];   // raw t tile, transposed [row][h], pad 132
  __shared__ ushort zb[128 * 128];   // LN output bf16, swizzled
  __shared__ ushort wt[128 * 128];   // Wo bf16, swizzled
  const int t = threadIdx.x, lane = t & 63, wid = t >> 6;
  const long base = (long)blockIdx.x * 128;

  // stage t (h-major -> [row][h] in LDS)
#pragma unroll
  for (int s2 = 0; s2 < 4; ++s2) {
    int id = t + s2 * 512;
    int h = id >> 4, part = id & 15;
    short8 v = *reinterpret_cast<const short8*>(t_in + (long)h * R + base + part * 8);
#pragma unroll
    for (int r = 0; r < 8; ++r) tt[(part * 8 + r) * 132 + h] = (ushort)v[r];
  }
  // stage Wo (fp32 -> bf16, swizzled)
#pragma unroll
  for (int s2 = 0; s2 < 8; ++s2) {
    int id = t + s2 * 512;
    int row = id >> 5, hb = id & 31;
    float4 v = *reinterpret_cast<const float4*>(Wo + row * 128 + hb * 4);
    ushort4 o = make_ushort4(f2bf(v.x), f2bf(v.y), f2bf(v.z), f2bf(v.w));
    *reinterpret_cast<ushort4*>(reinterpret_cast<char*>(wt) + row * 256 + ((hb * 8) ^ ((row & 7) << 4))) = o;
  }
  __syncthreads();
  // LN over h: wave handles 16 rows, lane covers 2 h
#pragma unroll
  for (int rr = 0; rr < 16; ++rr) {
    int row = wid * 16 + rr;
    ushort2 u = *reinterpret_cast<const ushort2*>(tt + row * 132 + lane * 2);
    float x0 = bf2f(u.x), x1 = bf2f(u.y);
    float s = x0 + x1, ss = x0 * x0 + x1 * x1;
#pragma unroll
    for (int off = 1; off < 64; off <<= 1) { s += __shfl_xor(s, off); ss += __shfl_xor(ss, off); }
    float mu = s * (1.f / H);
    float rs = rsqrtf(ss * (1.f / H) - mu * mu + 1e-5f);
    ushort2 ov;
    ov.x = f2bf((x0 - mu) * rs * lg[lane * 2] + lb[lane * 2]);
    ov.y = f2bf((x1 - mu) * rs * lg[lane * 2 + 1] + lb[lane * 2 + 1]);
    *reinterpret_cast<ushort2*>(reinterpret_cast<char*>(zb) + row * 256 + ((lane * 4) ^ ((row & 7) << 4))) = ov;
  }
  __syncthreads();

  f32x4 acc[8];
#pragma unroll
  for (int n2 = 0; n2 < 8; ++n2) acc[n2] = (f32x4)0.f;
  const int arow = wid * 16 + (lane & 15);
  const int kb0 = (lane >> 4) * 16;
#pragma unroll
  for (int kk = 0; kk < 4; ++kk) {
    int kbyte = kk * 64 + kb0;
    short8 af = *reinterpret_cast<const short8*>(reinterpret_cast<char*>(zb) + arow * 256 + (kbyte ^ ((arow & 7) << 4)));
#pragma unroll
    for (int n2 = 0; n2 < 8; ++n2) {
      int brow = n2 * 16 + (lane & 15);
      short8 bfr = *reinterpret_cast<const short8*>(reinterpret_cast<char*>(wt) + brow * 256 + (kbyte ^ ((brow & 7) << 4)));
      acc[n2] = __builtin_amdgcn_mfma_f32_16x16x32_bf16(af, bfr, acc[n2], 0, 0, 0);
    }
  }
#pragma unroll
  for (int n2 = 0; n2 < 8; ++n2) {
    int col = n2 * 16 + (lane & 15);
    float b1 = bo[col];
#pragma unroll
    for (int r = 0; r < 4; ++r) {
      long row = base + wid * 16 + (lane >> 4) * 4 + r;
      out[row * 128 + col] = (acc[n2][r] + b1) * bf2f(g_o[row * 128 + col]);
    }
  }
}

extern "C" void kernel_launch(void* const* d_in, const int* in_sizes, int n_in,
                              void* d_out, int out_size, void* d_ws, size_t ws_size,
                              hipStream_t stream) {
  const float* pair  = (const float*)d_in[0];
  const float* ln_g  = (const float*)d_in[1];
  const float* ln_b  = (const float*)d_in[2];
  const float* lnh_g = (const float*)d_in[3];
  const float* lnh_b = (const float*)d_in[4];
  const float* Wa  = (const float*)d_in[5];
  const float* ba  = (const float*)d_in[6];
  const float* Ga  = (const float*)d_in[7];
  const float* bga = (const float*)d_in[8];
  const float* Wb  = (const float*)d_in[9];
  const float* bb  = (const float*)d_in[10];
  const float* Gb  = (const float*)d_in[11];
  const float* bgb = (const float*)d_in[12];
  const float* Wo  = (const float*)d_in[13];
  const float* bo  = (const float*)d_in[14];
  const float* Wg  = (const float*)d_in[15];
  const float* bg  = (const float*)d_in[16];
  float* out = (float*)d_out;

  // workspace: 4 x 64 MiB = 256 MiB total
  char* ws = (char*)d_ws;
  ushort* a_t = (ushort*)(ws);                    // 64 MiB  bf16 [H][R]
  ushort* b_t = (ushort*)(ws + 67108864);         // 64 MiB  bf16 [H][R]
  ushort* t_w = (ushort*)(ws + 134217728);        // 64 MiB  bf16 [H][R]
  ushort* g_o = (ushort*)(ws + 201326592);        // 64 MiB  bf16 [R][C]

  k_proj<<<R / 128, 512, 0, stream>>>(pair, ln_g, ln_b, Wa, ba, Ga, bga, Wb, bb, Gb, bgb, Wg, bg, a_t, b_t, g_o);
  k_einsum<<<2048, 256, 0, stream>>>(a_t, b_t, t_w);
  k_out<<<R / 128, 512, 0, stream>>>(t_w, g_o, lnh_g, lnh_b, Wo, bo, out);
}

// Round 6
// 574.204 us; speedup vs baseline: 1.0266x; 1.0017x over previous
//
#include <hip/hip_runtime.h>

#define N 512
#define C 128
#define H 128
#define R (N * N)  // 262144 rows

typedef __attribute__((ext_vector_type(8))) short short8;  // 8 x bf16 (4 VGPRs)
typedef __attribute__((ext_vector_type(4))) float f32x4;

static __device__ __forceinline__ ushort f2bf(float f) {
  union { float f; unsigned int u; } x; x.f = f;
  unsigned int r = (x.u + 0x7fffu + ((x.u >> 16) & 1u)) >> 16;  // RNE
  return (ushort)r;
}
static __device__ __forceinline__ float bf2f(ushort u) {
  union { unsigned int i; float f; } x; x.i = ((unsigned int)u) << 16; return x.f;
}
static __device__ __forceinline__ float sig(float x) { return 1.f / (1.f + __expf(-x)); }

// ---------------- Kernel 1: fused LN(C) + 5-way projection -----------------
// 128-row tile/block, 8 waves (16 rows each). LN over C computed in-kernel
// (fp32 pair -> bf16 z tile in LDS), then 5 GEMMs against K=128-resident
// weights. ONLY change vs round-5-passing: the 34KB `ot` transpose buffer is
// deleted; combine_store stages through `wt` (dead at the call site — the
// pre-existing barriers before/after combine_store already make this
// race-free). LDS 98KB -> 64KB => 2 blocks/CU.
__global__ __launch_bounds__(512) void k_proj(
    const float* __restrict__ pair,
    const float* __restrict__ ln_g, const float* __restrict__ ln_b,
    const float* __restrict__ Wa, const float* __restrict__ ba,
    const float* __restrict__ Ga, const float* __restrict__ bga,
    const float* __restrict__ Wb, const float* __restrict__ bb,
    const float* __restrict__ Gb, const float* __restrict__ bgb,
    const float* __restrict__ Wg, const float* __restrict__ bg,
    ushort* __restrict__ a_t, ushort* __restrict__ b_t, ushort* __restrict__ g_o) {
  __shared__ ushort zt[128 * 128];   // LN'd z tile, swizzled, 32 KB
  __shared__ ushort wt[128 * 128];   // weight matrix / transpose staging, 32 KB
  const int t = threadIdx.x, lane = t & 63, wid = t >> 6;
  const long base = (long)blockIdx.x * 128;

  // --- fused LayerNorm over C: wave handles 16 rows, lane covers 2 channels
  const float2 gg = *reinterpret_cast<const float2*>(ln_g + lane * 2);
  const float2 gb = *reinterpret_cast<const float2*>(ln_b + lane * 2);
#pragma unroll
  for (int rr = 0; rr < 16; ++rr) {
    int row = wid * 16 + rr;
    const float2 v = *reinterpret_cast<const float2*>(pair + (base + row) * C + lane * 2);
    float s = v.x + v.y, ss = v.x * v.x + v.y * v.y;
#pragma unroll
    for (int off = 1; off < 64; off <<= 1) {
      s += __shfl_xor(s, off);
      ss += __shfl_xor(ss, off);
    }
    const float mu = s * (1.f / C);
    const float rs = rsqrtf(ss * (1.f / C) - mu * mu + 1e-5f);
    ushort2 o;
    o.x = f2bf((v.x - mu) * rs * gg.x + gb.x);
    o.y = f2bf((v.y - mu) * rs * gg.y + gb.y);
    // swizzled store: 4B granule; chunk-index XOR consistent with 16B reads
    *reinterpret_cast<ushort2*>(reinterpret_cast<char*>(zt) + row * 256 + ((lane * 4) ^ ((row & 7) << 4))) = o;
  }

  auto stage_w = [&](const float* __restrict__ W) {
#pragma unroll
    for (int s2 = 0; s2 < 8; ++s2) {
      int id = t + s2 * 512;             // [0,4096) float4 units
      int row = id >> 5, hb = id & 31;
      float4 v = *reinterpret_cast<const float4*>(W + row * 128 + hb * 4);
      ushort4 o = make_ushort4(f2bf(v.x), f2bf(v.y), f2bf(v.z), f2bf(v.w));
      *reinterpret_cast<ushort4*>(reinterpret_cast<char*>(wt) + row * 256 + ((hb * 8) ^ ((row & 7) << 4))) = o;
    }
  };

  const int arow = wid * 16 + (lane & 15);
  const int abase = arow * 256, asw = (arow & 7) << 4;
  const int kb0 = (lane >> 4) * 16;

  f32x4 accL[8], accG[8];
  auto mfma_pass = [&](f32x4* acc) {
#pragma unroll
    for (int n2 = 0; n2 < 8; ++n2) acc[n2] = (f32x4)0.f;
#pragma unroll
    for (int kk = 0; kk < 4; ++kk) {
      int kbyte = kk * 64 + kb0;
      short8 af = *reinterpret_cast<const short8*>(reinterpret_cast<char*>(zt) + abase + (kbyte ^ asw));
#pragma unroll
      for (int n2 = 0; n2 < 8; ++n2) {
        int brow = n2 * 16 + (lane & 15);
        short8 bfr = *reinterpret_cast<const short8*>(reinterpret_cast<char*>(wt) + brow * 256 + (kbyte ^ ((brow & 7) << 4)));
        acc[n2] = __builtin_amdgcn_mfma_f32_16x16x32_bf16(af, bfr, acc[n2], 0, 0, 0);
      }
    }
  };

  // fragment -> wt[col][row] (bf16, XOR-swizzled rows), then coalesced
  // h-major global write. wt's weight content is dead here (barriered).
  auto combine_store = [&](const float* __restrict__ bl, const float* __restrict__ bg2,
                           ushort* __restrict__ dst) {
#pragma unroll
    for (int n2 = 0; n2 < 8; ++n2) {
      int col = n2 * 16 + (lane & 15);
      float b1 = bl[col], b2 = bg2[col];
      union { ushort4 v; ushort e[4]; } o;
#pragma unroll
      for (int r = 0; r < 4; ++r)
        o.e[r] = f2bf((accL[n2][r] + b1) * sig(accG[n2][r] + b2));
      int rowb = wid * 16 + (lane >> 4) * 4;
      *reinterpret_cast<ushort4*>(reinterpret_cast<char*>(wt) + col * 256 + ((rowb * 2) ^ ((col & 7) << 4))) = o.v;
    }
    __syncthreads();
    // coalesced h-major global write: 256B per h-line
#pragma unroll
    for (int s2 = 0; s2 < 4; ++s2) {
      int id = t + s2 * 512;
      int h = id >> 4, part = id & 15;
      short8 v = *reinterpret_cast<const short8*>(reinterpret_cast<char*>(wt) + h * 256 + ((part * 16) ^ ((h & 7) << 4)));
      *reinterpret_cast<short8*>(dst + (long)h * R + base + part * 8) = v;
    }
  };

  stage_w(Wa); __syncthreads(); mfma_pass(accL); __syncthreads();
  stage_w(Ga); __syncthreads(); mfma_pass(accG); __syncthreads();
  combine_store(ba, bga, a_t); __syncthreads();
  stage_w(Wb); __syncthreads(); mfma_pass(accL); __syncthreads();
  stage_w(Gb); __syncthreads(); mfma_pass(accG); __syncthreads();
  combine_store(bb, bgb, b_t); __syncthreads();
  stage_w(Wg); __syncthreads(); mfma_pass(accL);
#pragma unroll
  for (int n2 = 0; n2 < 8; ++n2) {
    int col = n2 * 16 + (lane & 15);
    float b1 = bg[col];
#pragma unroll
    for (int r = 0; r < 4; ++r) {
      long row = base + wid * 16 + (lane >> 4) * 4 + r;
      g_o[row * 128 + col] = f2bf(sig(accL[n2][r] + b1));
    }
  }
}

// ---------------- Kernel 2: einsum = 128 x (512x512x512) NT GEMMs ----------
// t[h][i][j] = sum_k a_t[h][i][k] * b_t[h][j][k].  128x128 tile, BK=64, 4 waves.
// Unchanged from round-5-passing (flat-2048 + bijective XCD-chunked relabel).
__global__ __launch_bounds__(256) void k_einsum(const ushort* __restrict__ a_t,
                                                const ushort* __restrict__ b_t,
                                                ushort* __restrict__ t_out) {
  __shared__ ushort As[128 * 64];  // 16 KB, swizzled
  __shared__ ushort Bs[128 * 64];
  const int t = threadIdx.x, lane = t & 63, wid = t >> 6;
  const int flat = blockIdx.x;                 // 2048 = 8*256, bijective swizzle
  const int swz = (flat & 7) * 256 + (flat >> 3);
  const int h = swz >> 4, ti = (swz >> 2) & 3, tj = swz & 3;
  const ushort* A = a_t + (long)h * R;
  const ushort* B = b_t + (long)h * R;
  const int wm = wid >> 1, wn = wid & 1;  // 2x2 wave grid, 64x64 per wave

  f32x4 acc[4][4];
#pragma unroll
  for (int m = 0; m < 4; ++m)
#pragma unroll
    for (int n2 = 0; n2 < 4; ++n2) acc[m][n2] = (f32x4)0.f;

  for (int kt = 0; kt < 8; ++kt) {
    __syncthreads();
#pragma unroll
    for (int s2 = 0; s2 < 4; ++s2) {
      int id = t + s2 * 256;            // [0,1024): row(128) x kc(8) 16B chunks
      int row = id >> 3, kc = id & 7;
      int sbo = row * 128 + ((kc * 16) ^ ((row & 7) << 4));
      *reinterpret_cast<short8*>(reinterpret_cast<char*>(As) + sbo) =
          *reinterpret_cast<const short8*>(A + (ti * 128 + row) * 512 + kt * 64 + kc * 8);
      *reinterpret_cast<short8*>(reinterpret_cast<char*>(Bs) + sbo) =
          *reinterpret_cast<const short8*>(B + (tj * 128 + row) * 512 + kt * 64 + kc * 8);
    }
    __syncthreads();
#pragma unroll
    for (int kk = 0; kk < 2; ++kk) {
      int kbyte = kk * 64 + (lane >> 4) * 16;
      short8 af[4], bfr[4];
#pragma unroll
      for (int m = 0; m < 4; ++m) {
        int row = wm * 64 + m * 16 + (lane & 15);
        af[m] = *reinterpret_cast<const short8*>(reinterpret_cast<char*>(As) + row * 128 + (kbyte ^ ((row & 7) << 4)));
      }
#pragma unroll
      for (int n2 = 0; n2 < 4; ++n2) {
        int row = wn * 64 + n2 * 16 + (lane & 15);
        bfr[n2] = *reinterpret_cast<const short8*>(reinterpret_cast<char*>(Bs) + row * 128 + (kbyte ^ ((row & 7) << 4)));
      }
#pragma unroll
      for (int m = 0; m < 4; ++m)
#pragma unroll
        for (int n2 = 0; n2 < 4; ++n2)
          acc[m][n2] = __builtin_amdgcn_mfma_f32_16x16x32_bf16(af[m], bfr[n2], acc[m][n2], 0, 0, 0);
    }
  }
  ushort* T = t_out + (long)h * R;
#pragma unroll
  for (int m = 0; m < 4; ++m) {
    int row0 = ti * 128 + wm * 64 + m * 16 + (lane >> 4) * 4;
#pragma unroll
    for (int n2 = 0; n2 < 4; ++n2) {
      int col = tj * 128 + wn * 64 + n2 * 16 + (lane & 15);
#pragma unroll
      for (int r = 0; r < 4; ++r) T[(row0 + r) * 512 + col] = f2bf(acc[m][n2][r]);
    }
  }
}

// ---------------- Kernel 3: LN over H + @Wo^T + gating ---------------------
// Unchanged from round-5-passing.
__global__ __launch_bounds__(512) void k_out(
    const ushort* __restrict__ t_in, const ushort* __restrict__ g_o,
    const float* __restrict__ lg, const float* __restrict__ lb,
    const float* __restrict__ Wo, const float* __restrict__ bo,
    float* __restrict__ out) {
  __shared__ ushort tt[128 * 132];   // raw t tile, transposed [row][h], pad 132
  __shared__ ushort zb[128 * 128];   // LN output bf16, swizzled
  __shared__ ushort wt[128 * 128];   // Wo bf16, swizzled
  const int t = threadIdx.x, lane = t & 63, wid = t >> 6;
  const long base = (long)blockIdx.x * 128;

  // stage t (h-major -> [row][h] in LDS)
#pragma unroll
  for (int s2 = 0; s2 < 4; ++s2) {
    int id = t + s2 * 512;
    int h = id >> 4, part = id & 15;
    short8 v = *reinterpret_cast<const short8*>(t_in + (long)h * R + base + part * 8);
#pragma unroll
    for (int r = 0; r < 8; ++r) tt[(part * 8 + r) * 132 + h] = (ushort)v[r];
  }
  // stage Wo (fp32 -> bf16, swizzled)
#pragma unroll
  for (int s2 = 0; s2 < 8; ++s2) {
    int id = t + s2 * 512;
    int row = id >> 5, hb = id & 31;
    float4 v = *reinterpret_cast<const float4*>(Wo + row * 128 + hb * 4);
    ushort4 o = make_ushort4(f2bf(v.x), f2bf(v.y), f2bf(v.z), f2bf(v.w));
    *reinterpret_cast<ushort4*>(reinterpret_cast<char*>(wt) + row * 256 + ((hb * 8) ^ ((row & 7) << 4))) = o;
  }
  __syncthreads();
  // LN over h: wave handles 16 rows, lane covers 2 h
#pragma unroll
  for (int rr = 0; rr < 16; ++rr) {
    int row = wid * 16 + rr;
    ushort2 u = *reinterpret_cast<const ushort2*>(tt + row * 132 + lane * 2);
    float x0 = bf2f(u.x), x1 = bf2f(u.y);
    float s = x0 + x1, ss = x0 * x0 + x1 * x1;
#pragma unroll
    for (int off = 1; off < 64; off <<= 1) { s += __shfl_xor(s, off); ss += __shfl_xor(ss, off); }
    float mu = s * (1.f / H);
    float rs = rsqrtf(ss * (1.f / H) - mu * mu + 1e-5f);
    ushort2 ov;
    ov.x = f2bf((x0 - mu) * rs * lg[lane * 2] + lb[lane * 2]);
    ov.y = f2bf((x1 - mu) * rs * lg[lane * 2 + 1] + lb[lane * 2 + 1]);
    *reinterpret_cast<ushort2*>(reinterpret_cast<char*>(zb) + row * 256 + ((lane * 4) ^ ((row & 7) << 4))) = ov;
  }
  __syncthreads();

  f32x4 acc[8];
#pragma unroll
  for (int n2 = 0; n2 < 8; ++n2) acc[n2] = (f32x4)0.f;
  const int arow = wid * 16 + (lane & 15);
  const int kb0 = (lane >> 4) * 16;
#pragma unroll
  for (int kk = 0; kk < 4; ++kk) {
    int kbyte = kk * 64 + kb0;
    short8 af = *reinterpret_cast<const short8*>(reinterpret_cast<char*>(zb) + arow * 256 + (kbyte ^ ((arow & 7) << 4)));
#pragma unroll
    for (int n2 = 0; n2 < 8; ++n2) {
      int brow = n2 * 16 + (lane & 15);
      short8 bfr = *reinterpret_cast<const short8*>(reinterpret_cast<char*>(wt) + brow * 256 + (kbyte ^ ((brow & 7) << 4)));
      acc[n2] = __builtin_amdgcn_mfma_f32_16x16x32_bf16(af, bfr, acc[n2], 0, 0, 0);
    }
  }
#pragma unroll
  for (int n2 = 0; n2 < 8; ++n2) {
    int col = n2 * 16 + (lane & 15);
    float b1 = bo[col];
#pragma unroll
    for (int r = 0; r < 4; ++r) {
      long row = base + wid * 16 + (lane >> 4) * 4 + r;
      out[row * 128 + col] = (acc[n2][r] + b1) * bf2f(g_o[row * 128 + col]);
    }
  }
}

extern "C" void kernel_launch(void* const* d_in, const int* in_sizes, int n_in,
                              void* d_out, int out_size, void* d_ws, size_t ws_size,
                              hipStream_t stream) {
  const float* pair  = (const float*)d_in[0];
  const float* ln_g  = (const float*)d_in[1];
  const float* ln_b  = (const float*)d_in[2];
  const float* lnh_g = (const float*)d_in[3];
  const float* lnh_b = (const float*)d_in[4];
  const float* Wa  = (const float*)d_in[5];
  const float* ba  = (const float*)d_in[6];
  const float* Ga  = (const float*)d_in[7];
  const float* bga = (const float*)d_in[8];
  const float* Wb  = (const float*)d_in[9];
  const float* bb  = (const float*)d_in[10];
  const float* Gb  = (const float*)d_in[11];
  const float* bgb = (const float*)d_in[12];
  const float* Wo  = (const float*)d_in[13];
  const float* bo  = (const float*)d_in[14];
  const float* Wg  = (const float*)d_in[15];
  const float* bg  = (const float*)d_in[16];
  float* out = (float*)d_out;

  // workspace: 4 x 64 MiB = 256 MiB total
  char* ws = (char*)d_ws;
  ushort* a_t = (ushort*)(ws);                    // 64 MiB  bf16 [H][R]
  ushort* b_t = (ushort*)(ws + 67108864);         // 64 MiB  bf16 [H][R]
  ushort* t_w = (ushort*)(ws + 134217728);        // 64 MiB  bf16 [H][R]
  ushort* g_o = (ushort*)(ws + 201326592);        // 64 MiB  bf16 [R][C]

  k_proj<<<R / 128, 512, 0, stream>>>(pair, ln_g, ln_b, Wa, ba, Ga, bga, Wb, bb, Gb, bgb, Wg, bg, a_t, b_t, g_o);
  k_einsum<<<2048, 256, 0, stream>>>(a_t, b_t, t_w);
  k_out<<<R / 128, 512, 0, stream>>>(t_w, g_o, lnh_g, lnh_b, Wo, bo, out);
}

// Round 8
// 573.833 us; speedup vs baseline: 1.0272x; 1.0006x over previous
//
#include <hip/hip_runtime.h>

#define N 512
#define C 128
#define H 128
#define R (N * N)  // 262144 rows

typedef __attribute__((ext_vector_type(8))) short short8;  // 8 x bf16 (4 VGPRs)
typedef __attribute__((ext_vector_type(4))) float f32x4;

static __device__ __forceinline__ ushort f2bf(float f) {
  union { float f; unsigned int u; } x; x.f = f;
  unsigned int r = (x.u + 0x7fffu + ((x.u >> 16) & 1u)) >> 16;  // RNE
  return (ushort)r;
}
static __device__ __forceinline__ float bf2f(ushort u) {
  union { unsigned int i; float f; } x; x.i = ((unsigned int)u) << 16; return x.f;
}
static __device__ __forceinline__ float sig(float x) { return 1.f / (1.f + __expf(-x)); }

// ---------------- Kernel 1: fused LN(C) + 5-way projection -----------------
// 128-row tile/block, 8 waves (16 rows each). ONLY change vs round-7: the
// __launch_bounds__ min-waves pin is REMOVED (every failing round r3/r4/r7
// carried it; every passing round didn't — suspected spill-path miscompile).
// Register diet kept: gate pass first (Ga -> acc), sigmoid gate compressed to
// packed bf16 (8x uint2 = 16 VGPR), linear pass reuses the same acc array.
// Live set ~48 acc/gate regs vs r6's 64 AGPRs -> allocator should land <=128
// total naturally -> 2 blocks/CU without coercion.
__global__ __launch_bounds__(512) void k_proj(
    const float* __restrict__ pair,
    const float* __restrict__ ln_g, const float* __restrict__ ln_b,
    const float* __restrict__ Wa, const float* __restrict__ ba,
    const float* __restrict__ Ga, const float* __restrict__ bga,
    const float* __restrict__ Wb, const float* __restrict__ bb,
    const float* __restrict__ Gb, const float* __restrict__ bgb,
    const float* __restrict__ Wg, const float* __restrict__ bg,
    ushort* __restrict__ a_t, ushort* __restrict__ b_t, ushort* __restrict__ g_o) {
  __shared__ ushort zt[128 * 128];   // LN'd z tile, swizzled, 32 KB
  __shared__ ushort wt[128 * 128];   // weight matrix / transpose staging, 32 KB
  const int t = threadIdx.x, lane = t & 63, wid = t >> 6;
  const long base = (long)blockIdx.x * 128;

  // --- fused LayerNorm over C: wave handles 16 rows, lane covers 2 channels
  const float2 gg = *reinterpret_cast<const float2*>(ln_g + lane * 2);
  const float2 gb = *reinterpret_cast<const float2*>(ln_b + lane * 2);
#pragma unroll
  for (int rr = 0; rr < 16; ++rr) {
    int row = wid * 16 + rr;
    const float2 v = *reinterpret_cast<const float2*>(pair + (base + row) * C + lane * 2);
    float s = v.x + v.y, ss = v.x * v.x + v.y * v.y;
#pragma unroll
    for (int off = 1; off < 64; off <<= 1) {
      s += __shfl_xor(s, off);
      ss += __shfl_xor(ss, off);
    }
    const float mu = s * (1.f / C);
    const float rs = rsqrtf(ss * (1.f / C) - mu * mu + 1e-5f);
    ushort2 o;
    o.x = f2bf((v.x - mu) * rs * gg.x + gb.x);
    o.y = f2bf((v.y - mu) * rs * gg.y + gb.y);
    // swizzled store: 4B granule; chunk-index XOR consistent with 16B reads
    *reinterpret_cast<ushort2*>(reinterpret_cast<char*>(zt) + row * 256 + ((lane * 4) ^ ((row & 7) << 4))) = o;
  }

  auto stage_w = [&](const float* __restrict__ W) {
#pragma unroll
    for (int s2 = 0; s2 < 8; ++s2) {
      int id = t + s2 * 512;             // [0,4096) float4 units
      int row = id >> 5, hb = id & 31;
      float4 v = *reinterpret_cast<const float4*>(W + row * 128 + hb * 4);
      ushort4 o = make_ushort4(f2bf(v.x), f2bf(v.y), f2bf(v.z), f2bf(v.w));
      *reinterpret_cast<ushort4*>(reinterpret_cast<char*>(wt) + row * 256 + ((hb * 8) ^ ((row & 7) << 4))) = o;
    }
  };

  const int arow = wid * 16 + (lane & 15);
  const int abase = arow * 256, asw = (arow & 7) << 4;
  const int kb0 = (lane >> 4) * 16;

  f32x4 acc[8];      // single accumulator array (gate pass, then linear pass)
  uint2 gate[8];     // packed bf16 sigmoid gates (16 VGPRs)

  auto mfma_pass = [&]() {
#pragma unroll
    for (int n2 = 0; n2 < 8; ++n2) acc[n2] = (f32x4)0.f;
#pragma unroll
    for (int kk = 0; kk < 4; ++kk) {
      int kbyte = kk * 64 + kb0;
      short8 af = *reinterpret_cast<const short8*>(reinterpret_cast<char*>(zt) + abase + (kbyte ^ asw));
#pragma unroll
      for (int n2 = 0; n2 < 8; ++n2) {
        int brow = n2 * 16 + (lane & 15);
        short8 bfr = *reinterpret_cast<const short8*>(reinterpret_cast<char*>(wt) + brow * 256 + (kbyte ^ ((brow & 7) << 4)));
        acc[n2] = __builtin_amdgcn_mfma_f32_16x16x32_bf16(af, bfr, acc[n2], 0, 0, 0);
      }
    }
  };

  // compress sigmoid gate from acc (register-only; no LDS, no barrier impact)
  auto compress_gate = [&](const float* __restrict__ bg2) {
#pragma unroll
    for (int n2 = 0; n2 < 8; ++n2) {
      int col = n2 * 16 + (lane & 15);
      float b2 = bg2[col];
      unsigned int lo = (unsigned int)f2bf(sig(acc[n2][0] + b2)) |
                        ((unsigned int)f2bf(sig(acc[n2][1] + b2)) << 16);
      unsigned int hi = (unsigned int)f2bf(sig(acc[n2][2] + b2)) |
                        ((unsigned int)f2bf(sig(acc[n2][3] + b2)) << 16);
      gate[n2] = make_uint2(lo, hi);
    }
  };

  // fragment -> wt[col][row] (bf16, XOR-swizzled rows), then coalesced
  // h-major global write. wt's weight content is dead here (barriered).
  auto combine_store = [&](const float* __restrict__ bl, ushort* __restrict__ dst) {
#pragma unroll
    for (int n2 = 0; n2 < 8; ++n2) {
      int col = n2 * 16 + (lane & 15);
      float b1 = bl[col];
      float g4[4];
      g4[0] = bf2f((ushort)(gate[n2].x & 0xffffu));
      g4[1] = bf2f((ushort)(gate[n2].x >> 16));
      g4[2] = bf2f((ushort)(gate[n2].y & 0xffffu));
      g4[3] = bf2f((ushort)(gate[n2].y >> 16));
      union { ushort4 v; ushort e[4]; } o;
#pragma unroll
      for (int r = 0; r < 4; ++r)
        o.e[r] = f2bf((acc[n2][r] + b1) * g4[r]);
      int rowb = wid * 16 + (lane >> 4) * 4;
      *reinterpret_cast<ushort4*>(reinterpret_cast<char*>(wt) + col * 256 + ((rowb * 2) ^ ((col & 7) << 4))) = o.v;
    }
    __syncthreads();
    // coalesced h-major global write: 256B per h-line
#pragma unroll
    for (int s2 = 0; s2 < 4; ++s2) {
      int id = t + s2 * 512;
      int h = id >> 4, part = id & 15;
      short8 v = *reinterpret_cast<const short8*>(reinterpret_cast<char*>(wt) + h * 256 + ((part * 16) ^ ((h & 7) << 4)));
      *reinterpret_cast<short8*>(dst + (long)h * R + base + part * 8) = v;
    }
  };

  // output a: gate pass (Ga) -> compress -> linear pass (Wa) -> combine
  stage_w(Ga); __syncthreads(); mfma_pass(); __syncthreads();
  compress_gate(bga);
  stage_w(Wa); __syncthreads(); mfma_pass(); __syncthreads();
  combine_store(ba, a_t); __syncthreads();
  // output b
  stage_w(Gb); __syncthreads(); mfma_pass(); __syncthreads();
  compress_gate(bgb);
  stage_w(Wb); __syncthreads(); mfma_pass(); __syncthreads();
  combine_store(bb, b_t); __syncthreads();
  // output g_o
  stage_w(Wg); __syncthreads(); mfma_pass();
#pragma unroll
  for (int n2 = 0; n2 < 8; ++n2) {
    int col = n2 * 16 + (lane & 15);
    float b1 = bg[col];
#pragma unroll
    for (int r = 0; r < 4; ++r) {
      long row = base + wid * 16 + (lane >> 4) * 4 + r;
      g_o[row * 128 + col] = f2bf(sig(acc[n2][r] + b1));
    }
  }
}

// ---------------- Kernel 2: einsum = 128 x (512x512x512) NT GEMMs ----------
// t[h][i][j] = sum_k a_t[h][i][k] * b_t[h][j][k].  128x128 tile, BK=64, 4 waves.
// Unchanged from round-6-passing (flat-2048 + bijective XCD-chunked relabel).
__global__ __launch_bounds__(256) void k_einsum(const ushort* __restrict__ a_t,
                                                const ushort* __restrict__ b_t,
                                                ushort* __restrict__ t_out) {
  __shared__ ushort As[128 * 64];  // 16 KB, swizzled
  __shared__ ushort Bs[128 * 64];
  const int t = threadIdx.x, lane = t & 63, wid = t >> 6;
  const int flat = blockIdx.x;                 // 2048 = 8*256, bijective swizzle
  const int swz = (flat & 7) * 256 + (flat >> 3);
  const int h = swz >> 4, ti = (swz >> 2) & 3, tj = swz & 3;
  const ushort* A = a_t + (long)h * R;
  const ushort* B = b_t + (long)h * R;
  const int wm = wid >> 1, wn = wid & 1;  // 2x2 wave grid, 64x64 per wave

  f32x4 acc[4][4];
#pragma unroll
  for (int m = 0; m < 4; ++m)
#pragma unroll
    for (int n2 = 0; n2 < 4; ++n2) acc[m][n2] = (f32x4)0.f;

  for (int kt = 0; kt < 8; ++kt) {
    __syncthreads();
#pragma unroll
    for (int s2 = 0; s2 < 4; ++s2) {
      int id = t + s2 * 256;            // [0,1024): row(128) x kc(8) 16B chunks
      int row = id >> 3, kc = id & 7;
      int sbo = row * 128 + ((kc * 16) ^ ((row & 7) << 4));
      *reinterpret_cast<short8*>(reinterpret_cast<char*>(As) + sbo) =
          *reinterpret_cast<const short8*>(A + (ti * 128 + row) * 512 + kt * 64 + kc * 8);
      *reinterpret_cast<short8*>(reinterpret_cast<char*>(Bs) + sbo) =
          *reinterpret_cast<const short8*>(B + (tj * 128 + row) * 512 + kt * 64 + kc * 8);
    }
    __syncthreads();
#pragma unroll
    for (int kk = 0; kk < 2; ++kk) {
      int kbyte = kk * 64 + (lane >> 4) * 16;
      short8 af[4], bfr[4];
#pragma unroll
      for (int m = 0; m < 4; ++m) {
        int row = wm * 64 + m * 16 + (lane & 15);
        af[m] = *reinterpret_cast<const short8*>(reinterpret_cast<char*>(As) + row * 128 + (kbyte ^ ((row & 7) << 4)));
      }
#pragma unroll
      for (int n2 = 0; n2 < 4; ++n2) {
        int row = wn * 64 + n2 * 16 + (lane & 15);
        bfr[n2] = *reinterpret_cast<const short8*>(reinterpret_cast<char*>(Bs) + row * 128 + (kbyte ^ ((row & 7) << 4)));
      }
#pragma unroll
      for (int m = 0; m < 4; ++m)
#pragma unroll
        for (int n2 = 0; n2 < 4; ++n2)
          acc[m][n2] = __builtin_amdgcn_mfma_f32_16x16x32_bf16(af[m], bfr[n2], acc[m][n2], 0, 0, 0);
    }
  }
  ushort* T = t_out + (long)h * R;
#pragma unroll
  for (int m = 0; m < 4; ++m) {
    int row0 = ti * 128 + wm * 64 + m * 16 + (lane >> 4) * 4;
#pragma unroll
    for (int n2 = 0; n2 < 4; ++n2) {
      int col = tj * 128 + wn * 64 + n2 * 16 + (lane & 15);
#pragma unroll
      for (int r = 0; r < 4; ++r) T[(row0 + r) * 512 + col] = f2bf(acc[m][n2][r]);
    }
  }
}

// ---------------- Kernel 3: LN over H + @Wo^T + gating ---------------------
// Unchanged from round-6-passing.
__global__ __launch_bounds__(512) void k_out(
    const ushort* __restrict__ t_in, const ushort* __restrict__ g_o,
    const float* __restrict__ lg, const float* __restrict__ lb,
    const float* __restrict__ Wo, const float* __restrict__ bo,
    float* __restrict__ out) {
  __shared__ ushort tt[128 * 132];   // raw t tile, transposed [row][h], pad 132
  __shared__ ushort zb[128 * 128];   // LN output bf16, swizzled
  __shared__ ushort wt[128 * 128];   // Wo bf16, swizzled
  const int t = threadIdx.x, lane = t & 63, wid = t >> 6;
  const long base = (long)blockIdx.x * 128;

  // stage t (h-major -> [row][h] in LDS)
#pragma unroll
  for (int s2 = 0; s2 < 4; ++s2) {
    int id = t + s2 * 512;
    int h = id >> 4, part = id & 15;
    short8 v = *reinterpret_cast<const short8*>(t_in + (long)h * R + base + part * 8);
#pragma unroll
    for (int r = 0; r < 8; ++r) tt[(part * 8 + r) * 132 + h] = (ushort)v[r];
  }
  // stage Wo (fp32 -> bf16, swizzled)
#pragma unroll
  for (int s2 = 0; s2 < 8; ++s2) {
    int id = t + s2 * 512;
    int row = id >> 5, hb = id & 31;
    float4 v = *reinterpret_cast<const float4*>(Wo + row * 128 + hb * 4);
    ushort4 o = make_ushort4(f2bf(v.x), f2bf(v.y), f2bf(v.z), f2bf(v.w));
    *reinterpret_cast<ushort4*>(reinterpret_cast<char*>(wt) + row * 256 + ((hb * 8) ^ ((row & 7) << 4))) = o;
  }
  __syncthreads();
  // LN over h: wave handles 16 rows, lane covers 2 h
#pragma unroll
  for (int rr = 0; rr < 16; ++rr) {
    int row = wid * 16 + rr;
    ushort2 u = *reinterpret_cast<const ushort2*>(tt + row * 132 + lane * 2);
    float x0 = bf2f(u.x), x1 = bf2f(u.y);
    float s = x0 + x1, ss = x0 * x0 + x1 * x1;
#pragma unroll
    for (int off = 1; off < 64; off <<= 1) { s += __shfl_xor(s, off); ss += __shfl_xor(ss, off); }
    float mu = s * (1.f / H);
    float rs = rsqrtf(ss * (1.f / H) - mu * mu + 1e-5f);
    ushort2 ov;
    ov.x = f2bf((x0 - mu) * rs * lg[lane * 2] + lb[lane * 2]);
    ov.y = f2bf((x1 - mu) * rs * lg[lane * 2 + 1] + lb[lane * 2 + 1]);
    *reinterpret_cast<ushort2*>(reinterpret_cast<char*>(zb) + row * 256 + ((lane * 4) ^ ((row & 7) << 4))) = ov;
  }
  __syncthreads();

  f32x4 acc[8];
#pragma unroll
  for (int n2 = 0; n2 < 8; ++n2) acc[n2] = (f32x4)0.f;
  const int arow = wid * 16 + (lane & 15);
  const int kb0 = (lane >> 4) * 16;
#pragma unroll
  for (int kk = 0; kk < 4; ++kk) {
    int kbyte = kk * 64 + kb0;
    short8 af = *reinterpret_cast<const short8*>(reinterpret_cast<char*>(zb) + arow * 256 + (kbyte ^ ((arow & 7) << 4)));
#pragma unroll
    for (int n2 = 0; n2 < 8; ++n2) {
      int brow = n2 * 16 + (lane & 15);
      short8 bfr = *reinterpret_cast<const short8*>(reinterpret_cast<char*>(wt) + brow * 256 + (kbyte ^ ((brow & 7) << 4)));
      acc[n2] = __builtin_amdgcn_mfma_f32_16x16x32_bf16(af, bfr, acc[n2], 0, 0, 0);
    }
  }
#pragma unroll
  for (int n2 = 0; n2 < 8; ++n2) {
    int col = n2 * 16 + (lane & 15);
    float b1 = bo[col];
#pragma unroll
    for (int r = 0; r < 4; ++r) {
      long row = base + wid * 16 + (lane >> 4) * 4 + r;
      out[row * 128 + col] = (acc[n2][r] + b1) * bf2f(g_o[row * 128 + col]);
    }
  }
}

extern "C" void kernel_launch(void* const* d_in, const int* in_sizes, int n_in,
                              void* d_out, int out_size, void* d_ws, size_t ws_size,
                              hipStream_t stream) {
  const float* pair  = (const float*)d_in[0];
  const float* ln_g  = (const float*)d_in[1];
  const float* ln_b  = (const float*)d_in[2];
  const float* lnh_g = (const float*)d_in[3];
  const float* lnh_b = (const float*)d_in[4];
  const float* Wa  = (const float*)d_in[5];
  const float* ba  = (const float*)d_in[6];
  const float* Ga  = (const float*)d_in[7];
  const float* bga = (const float*)d_in[8];
  const float* Wb  = (const float*)d_in[9];
  const float* bb  = (const float*)d_in[10];
  const float* Gb  = (const float*)d_in[11];
  const float* bgb = (const float*)d_in[12];
  const float* Wo  = (const float*)d_in[13];
  const float* bo  = (const float*)d_in[14];
  const float* Wg  = (const float*)d_in[15];
  const float* bg  = (const float*)d_in[16];
  float* out = (float*)d_out;

  // workspace: 4 x 64 MiB = 256 MiB total
  char* ws = (char*)d_ws;
  ushort* a_t = (ushort*)(ws);                    // 64 MiB  bf16 [H][R]
  ushort* b_t = (ushort*)(ws + 67108864);         // 64 MiB  bf16 [H][R]
  ushort* t_w = (ushort*)(ws + 134217728);        // 64 MiB  bf16 [H][R]
  ushort* g_o = (ushort*)(ws + 201326592);        // 64 MiB  bf16 [R][C]

  k_proj<<<R / 128, 512, 0, stream>>>(pair, ln_g, ln_b, Wa, ba, Ga, bga, Wb, bb, Gb, bgb, Wg, bg, a_t, b_t, g_o);
  k_einsum<<<2048, 256, 0, stream>>>(a_t, b_t, t_w);
  k_out<<<R / 128, 512, 0, stream>>>(t_w, g_o, lnh_g, lnh_b, Wo, bo, out);
}